// Round 8
// baseline (176.538 us; speedup 1.0000x reference)
//
#include <hip/hip_runtime.h>
#include <hip/hip_bf16.h>

// Single-head causal attention. x:[8,2048,1024] f32, W*:[1024,64] f32 -> out f32.
// v4: (0) wtrans: coalesced W -> bf16 W^T [192][1024], q-scale folded.
//     (1) qkv: register-only GEMM, 16-row blocks x 1024, 4-way K-split; V written TRANSPOSED (vT[64][BT]).
//     (2) attn: 32-row q-tiles x 512 blocks (big-first), 4 waves, vectorized K/V^T staging.

typedef __attribute__((ext_vector_type(8))) __bf16 bf16x8;
typedef __attribute__((ext_vector_type(4))) float f32x4;

#define BT   16384
#define TLEN 2048
#define NB   8

__device__ __forceinline__ ushort f2bf(float f) {
    __hip_bfloat16 h = __float2bfloat16(f);     // RNE
    return __builtin_bit_cast(ushort, h);
}

// ---------------- Kernel 0: W -> W^T bf16 (q-scale folded), coalesced ----------
__global__ void wtrans_kernel(const float* __restrict__ Wk, const float* __restrict__ Wq,
                              const float* __restrict__ Wv, ushort* __restrict__ wtb) {
    int idx = blockIdx.x * 256 + threadIdx.x;   // 192 blocks
    int e   = idx * 4;                          // flat over [3][1024][64]
    int s   = e >> 16;
    int rem = e & 65535;
    int k   = rem >> 6;
    int h   = rem & 63;
    const float* W = (s == 0) ? Wk : (s == 1) ? Wq : Wv;
    float sc = (s == 1) ? 0.125f : 1.0f;
    float4 v = *reinterpret_cast<const float4*>(&W[(size_t)k * 64 + h]);
    wtb[(size_t)(s * 64 + h + 0) * 1024 + k] = f2bf(v.x * sc);
    wtb[(size_t)(s * 64 + h + 1) * 1024 + k] = f2bf(v.y * sc);
    wtb[(size_t)(s * 64 + h + 2) * 1024 + k] = f2bf(v.z * sc);
    wtb[(size_t)(s * 64 + h + 3) * 1024 + k] = f2bf(v.w * sc);
}

// ---------------- Kernel 1: QKV projection, register-only, 16-row blocks -------
// Grid 1024 x 256 threads. Block rows R0..R0+16. 4 waves = 4 K-quarters.
// K(s=0), Q(s=1) stored row-major [BT][64]; V(s=2) stored TRANSPOSED vT[64][BT].
__global__ __launch_bounds__(256, 4) void qkv_kernel4(
    const float* __restrict__ x, const ushort* __restrict__ wtb,
    ushort* __restrict__ kqv, ushort* __restrict__ vT)
{
    __shared__ __align__(16) f32x4 red[2][12][64];   // 24 KB, epilogue only

    const int tid  = threadIdx.x;
    const int lane = tid & 63;
    const int h    = tid >> 6;          // K-quarter
    const int m    = lane & 15;
    const int g    = lane >> 4;
    const int R0   = blockIdx.x * 16;

    f32x4 acc[12];
    #pragma unroll
    for (int i = 0; i < 12; ++i) acc[i] = (f32x4){0.f, 0.f, 0.f, 0.f};

    const float*  xp = &x[(size_t)(R0 + m) * 1024 + h * 256 + g * 8];
    const ushort* wb = &wtb[(size_t)m * 1024 + h * 256 + g * 8];

    float4 xa = *reinterpret_cast<const float4*>(xp);
    float4 xb = *reinterpret_cast<const float4*>(xp + 4);

    #pragma unroll
    for (int st = 0; st < 8; ++st) {
        float4 xna, xnb;
        if (st < 7) {
            xna = *reinterpret_cast<const float4*>(xp + (st + 1) * 32);
            xnb = *reinterpret_cast<const float4*>(xp + (st + 1) * 32 + 4);
        }
        union { ushort u[8]; bf16x8 v; } av;
        av.u[0] = f2bf(xa.x); av.u[1] = f2bf(xa.y); av.u[2] = f2bf(xa.z); av.u[3] = f2bf(xa.w);
        av.u[4] = f2bf(xb.x); av.u[5] = f2bf(xb.y); av.u[6] = f2bf(xb.z); av.u[7] = f2bf(xb.w);
        #pragma unroll
        for (int nt = 0; nt < 12; ++nt) {
            bf16x8 b = *reinterpret_cast<const bf16x8*>(wb + (size_t)nt * 16 * 1024 + st * 32);
            acc[nt] = __builtin_amdgcn_mfma_f32_16x16x32_bf16(av.v, b, acc[nt], 0, 0, 0);
        }
        xa = xna; xb = xnb;
    }

    // reduce 4 K-quarters: h1->red0, h3->red1; h0+=red0, h2+=red1; h2->red0; h0+=red0
    if (h == 1 || h == 3) {
        #pragma unroll
        for (int i = 0; i < 12; ++i) red[h >> 1][i][lane] = acc[i];
    }
    __syncthreads();
    if (h == 0 || h == 2) {
        #pragma unroll
        for (int i = 0; i < 12; ++i) acc[i] += red[h >> 1][i][lane];
    }
    __syncthreads();
    if (h == 2) {
        #pragma unroll
        for (int i = 0; i < 12; ++i) red[0][i][lane] = acc[i];
    }
    __syncthreads();
    if (h == 0) {
        #pragma unroll
        for (int nt = 0; nt < 12; ++nt) {
            f32x4 a = acc[nt] + red[0][nt][lane];
            int s = nt >> 2;
            int c = (nt & 3) * 16 + m;
            #pragma unroll
            for (int j = 0; j < 4; ++j) {
                size_t row = (size_t)R0 + g * 4 + j;     // C/D: row=(lane>>4)*4+j
                if (s < 2) kqv[((size_t)s * BT + row) * 64 + c] = f2bf(a[j]);
                else       vT[(size_t)c * BT + row]            = f2bf(a[j]);
            }
        }
    }
}

// ---------------- Kernel 2: flash causal attention, 32-row q-tiles -------------
// Grid 512 (big-tiles-first) x 256 threads. Waves: wq = wv&1 (16-row half),
// hf = wv>>1 (even/odd kv tile). Ti = i/2+1 kv tiles. 2-way merge at end.
__global__ __launch_bounds__(256, 3) void attn_kernel3(
    const ushort* __restrict__ qs, const ushort* __restrict__ ks,
    const ushort* __restrict__ vT, float* __restrict__ out)
{
    __shared__ __align__(16) ushort kt[2][64][80];   // K tile [kv][c], stride 160B
    __shared__ __align__(16) ushort vt[2][64][80];   // V^T tile [h][kv]
    __shared__ __align__(16) ushort pl[4][16][72];   // per-wave P tile

    const int bid = blockIdx.x;
    const int i   = 63 - (bid >> 3);    // q-tile (32 rows), largest Ti first
    const int b   = bid & 7;
    const int Ti  = (i >> 1) + 1;       // kv tiles for this q-tile

    const int tid  = threadIdx.x;
    const int lane = tid & 63;
    const int wv   = tid >> 6;
    const int wq   = wv & 1;
    const int hf   = wv >> 1;
    const int m    = lane & 15;
    const int g    = lane >> 4;
    const int ko   = g * 8;
    const int rowb = g * 4;
    const size_t base = (size_t)b * TLEN;
    const int qr0 = i * 32 + wq * 16;   // wave's first q row (within batch)

    bf16x8 qa[2];
    {
        size_t row_g = base + qr0 + m;
        qa[0] = *reinterpret_cast<const bf16x8*>(&qs[row_g * 64 + 0 + ko]);
        qa[1] = *reinterpret_cast<const bf16x8*>(&qs[row_g * 64 + 32 + ko]);
    }

    f32x4 o[4];
    #pragma unroll
    for (int nt = 0; nt < 4; ++nt) o[nt] = (f32x4){0.f, 0.f, 0.f, 0.f};
    float mrun[4] = {-1e30f, -1e30f, -1e30f, -1e30f};
    float lrun[4] = {0.f, 0.f, 0.f, 0.f};

    // staging map: 128 threads per tile-parity; 64B per thread, all vectorized
    const int hs2 = tid >> 7;           // tile parity this thread stages
    const int tl  = tid & 127;
    const int sr  = tl >> 1;            // K row / V^T h-row
    const int sh  = (tl & 1) * 32;      // column offset (ushorts)

    const int nit = (Ti + 1) >> 1;
    for (int it = 0; it < nit; ++it) {
        int ts = 2 * it + hs2;
        if (ts < Ti) {
            const ushort* ksrc = &ks[(base + (size_t)ts * 64 + sr) * 64 + sh];
            uint4* kdst = reinterpret_cast<uint4*>(&kt[hs2][sr][sh]);
            #pragma unroll
            for (int q = 0; q < 4; ++q) kdst[q] = reinterpret_cast<const uint4*>(ksrc)[q];
            const ushort* vsrc = &vT[(size_t)sr * BT + base + (size_t)ts * 64 + sh];
            uint4* vdst = reinterpret_cast<uint4*>(&vt[hs2][sr][sh]);
            #pragma unroll
            for (int q = 0; q < 4; ++q) vdst[q] = reinterpret_cast<const uint4*>(vsrc)[q];
        }
        __syncthreads();

        int t = 2 * it + hf;
        if (t < Ti) {
            f32x4 s[4];
            #pragma unroll
            for (int nt = 0; nt < 4; ++nt) s[nt] = (f32x4){0.f, 0.f, 0.f, 0.f};
            #pragma unroll
            for (int kk = 0; kk < 2; ++kk) {
                #pragma unroll
                for (int nt = 0; nt < 4; ++nt) {
                    bf16x8 bb = *reinterpret_cast<const bf16x8*>(&kt[hf][nt * 16 + m][kk * 32 + ko]);
                    s[nt] = __builtin_amdgcn_mfma_f32_16x16x32_bf16(qa[kk], bb, s[nt], 0, 0, 0);
                }
            }
            if (t == Ti - 1) {          // diagonal tile: causal mask
                #pragma unroll
                for (int nt = 0; nt < 4; ++nt)
                    #pragma unroll
                    for (int j = 0; j < 4; ++j)
                        if (t * 64 + nt * 16 + m > qr0 + rowb + j) s[nt][j] = -1e30f;
            }
            #pragma unroll
            for (int j = 0; j < 4; ++j) {
                float mx = fmaxf(fmaxf(s[0][j], s[1][j]), fmaxf(s[2][j], s[3][j]));
                #pragma unroll
                for (int d = 1; d < 16; d <<= 1) mx = fmaxf(mx, __shfl_xor(mx, d, 64));
                float mnew = fmaxf(mrun[j], mx);
                float corr = __expf(mrun[j] - mnew);
                mrun[j] = mnew;
                float p0 = __expf(s[0][j] - mnew);
                float p1 = __expf(s[1][j] - mnew);
                float p2 = __expf(s[2][j] - mnew);
                float p3 = __expf(s[3][j] - mnew);
                float ps = p0 + p1 + p2 + p3;
                #pragma unroll
                for (int d = 1; d < 16; d <<= 1) ps += __shfl_xor(ps, d, 64);
                lrun[j] = lrun[j] * corr + ps;
                #pragma unroll
                for (int nt = 0; nt < 4; ++nt) o[nt][j] *= corr;
                pl[wv][rowb + j][0 * 16 + m] = f2bf(p0);
                pl[wv][rowb + j][1 * 16 + m] = f2bf(p1);
                pl[wv][rowb + j][2 * 16 + m] = f2bf(p2);
                pl[wv][rowb + j][3 * 16 + m] = f2bf(p3);
            }
            // P exchange is wave-local; drain DS writes then fence the scheduler.
            asm volatile("s_waitcnt lgkmcnt(0)" ::: "memory");
            __builtin_amdgcn_sched_barrier(0);
            #pragma unroll
            for (int kk = 0; kk < 2; ++kk) {
                bf16x8 pa = *reinterpret_cast<const bf16x8*>(&pl[wv][m][kk * 32 + ko]);
                #pragma unroll
                for (int nt = 0; nt < 4; ++nt) {
                    bf16x8 vb = *reinterpret_cast<const bf16x8*>(&vt[hf][nt * 16 + m][kk * 32 + ko]);
                    o[nt] = __builtin_amdgcn_mfma_f32_16x16x32_bf16(pa, vb, o[nt], 0, 0, 0);
                }
            }
        }
        __syncthreads();
    }

    // ---- merge kv-parities: hf=1 publishes, hf=0 combines & stores ----
    float* mg = reinterpret_cast<float*>(&kt[0][0][0]);   // [2][4][64] f32x4 = 8 KB
    float* st = reinterpret_cast<float*>(&vt[0][0][0]);   // [32][2] f32
    if (hf == 1) {
        #pragma unroll
        for (int nt = 0; nt < 4; ++nt)
            *reinterpret_cast<f32x4*>(&mg[((wq * 4 + nt) * 64 + lane) * 4]) = o[nt];
        if (m == 0) {
            #pragma unroll
            for (int j = 0; j < 4; ++j) {
                st[(wq * 16 + rowb + j) * 2 + 0] = mrun[j];
                st[(wq * 16 + rowb + j) * 2 + 1] = lrun[j];
            }
        }
    }
    __syncthreads();
    if (hf == 0) {
        float ea[4], eb[4], li[4];
        #pragma unroll
        for (int j = 0; j < 4; ++j) {
            float m1 = st[(wq * 16 + rowb + j) * 2 + 0];
            float l1 = st[(wq * 16 + rowb + j) * 2 + 1];
            float mm = fmaxf(mrun[j], m1);
            ea[j] = __expf(mrun[j] - mm);
            eb[j] = __expf(m1 - mm);
            li[j] = 1.0f / (lrun[j] * ea[j] + l1 * eb[j]);
        }
        #pragma unroll
        for (int nt = 0; nt < 4; ++nt) {
            f32x4 ob = *reinterpret_cast<const f32x4*>(&mg[((wq * 4 + nt) * 64 + lane) * 4]);
            #pragma unroll
            for (int j = 0; j < 4; ++j) {
                size_t rrow = base + qr0 + rowb + j;
                out[rrow * 64 + nt * 16 + m] = (o[nt][j] * ea[j] + ob[j] * eb[j]) * li[j];
            }
        }
    }
}

extern "C" void kernel_launch(void* const* d_in, const int* in_sizes, int n_in,
                              void* d_out, int out_size, void* d_ws, size_t ws_size,
                              hipStream_t stream) {
    const float* x  = (const float*)d_in[0];
    const float* Wk = (const float*)d_in[1];
    const float* Wq = (const float*)d_in[2];
    const float* Wv = (const float*)d_in[3];
    float* out = (float*)d_out;

    // ws: K [BT][64] | Q [BT][64] | vT [64][BT]  (bf16, 6 MB) | W^T [192][1024] (384 KB)
    ushort* ws   = (ushort*)d_ws;
    ushort* kqv  = ws;                              // K,Q row-major blocks
    ushort* kbuf = ws;
    ushort* qbuf = ws + (size_t)BT * 64;
    ushort* vTb  = ws + (size_t)2 * BT * 64;        // V transposed [64][BT]
    ushort* wtb  = ws + (size_t)3 * BT * 64;

    wtrans_kernel<<<dim3(192), 256, 0, stream>>>(Wk, Wq, Wv, wtb);
    qkv_kernel4<<<dim3(1024), 256, 0, stream>>>(x, wtb, kqv, vTb);
    attn_kernel3<<<dim3(512), 256, 0, stream>>>(qbuf, kbuf, vTb, out);
}

// Round 9
// 158.044 us; speedup vs baseline: 1.1170x; 1.1170x over previous
//
#include <hip/hip_runtime.h>
#include <hip/hip_bf16.h>

// Single-head causal attention. x:[8,2048,1024] f32, W*:[1024,64] f32 -> out f32.
// v5: (0) wtrans: coalesced W -> bf16 W^T [192][1024], q-scale folded.
//     (1) qkv: coalesced LDS-staged GEMM, XOR-swizzled tiles, T14 async prefetch,
//         512 blocks x 32 rows, double-buffered. V written TRANSPOSED (vT[64][BT]).
//     (2) attn: 32-row q-tiles x 512 blocks (big-first), 4 waves (unchanged).

typedef __attribute__((ext_vector_type(8))) __bf16 bf16x8;
typedef __attribute__((ext_vector_type(4))) float f32x4;

#define BT   16384
#define TLEN 2048
#define NB   8

__device__ __forceinline__ ushort f2bf(float f) {
    __hip_bfloat16 h = __float2bfloat16(f);     // RNE
    return __builtin_bit_cast(ushort, h);
}

// ---------------- Kernel 0: W -> W^T bf16 (q-scale folded), coalesced ----------
__global__ void wtrans_kernel(const float* __restrict__ Wk, const float* __restrict__ Wq,
                              const float* __restrict__ Wv, ushort* __restrict__ wtb) {
    int idx = blockIdx.x * 256 + threadIdx.x;   // 192 blocks
    int e   = idx * 4;                          // flat over [3][1024][64]
    int s   = e >> 16;
    int rem = e & 65535;
    int k   = rem >> 6;
    int h   = rem & 63;
    const float* W = (s == 0) ? Wk : (s == 1) ? Wq : Wv;
    float sc = (s == 1) ? 0.125f : 1.0f;
    float4 v = *reinterpret_cast<const float4*>(&W[(size_t)k * 64 + h]);
    wtb[(size_t)(s * 64 + h + 0) * 1024 + k] = f2bf(v.x * sc);
    wtb[(size_t)(s * 64 + h + 1) * 1024 + k] = f2bf(v.y * sc);
    wtb[(size_t)(s * 64 + h + 2) * 1024 + k] = f2bf(v.z * sc);
    wtb[(size_t)(s * 64 + h + 3) * 1024 + k] = f2bf(v.w * sc);
}

// ---------------- Kernel 1: QKV projection, coalesced LDS-staged GEMM ----------
// Grid 512 x 256 threads. Block rows R0..R0+32, full K=1024 in 16 tiles of 64.
// 4 waves = (row-half r in {0,1}) x (col-half ch in {0,1}); wave = 16 rows x 96 cols.
// x staged [32][64] f32->bf16, W^T staged [192][64] bf16; both XOR-swizzled
// (16B chunk ^ (row&7)); double-buffered; next-tile loads issued before compute.
__global__ __launch_bounds__(256, 2) void qkv_kernel5(
    const float* __restrict__ x, const ushort* __restrict__ wtb,
    ushort* __restrict__ kq, ushort* __restrict__ vT)
{
    __shared__ __align__(16) ushort xs[2][32 * 64];    //  8 KB
    __shared__ __align__(16) ushort bs[2][192 * 64];   // 48 KB

    const int tid  = threadIdx.x;
    const int lane = tid & 63;
    const int wv   = tid >> 6;
    const int r    = wv & 1;           // row half (16 rows)
    const int ch   = wv >> 1;          // col half (96 cols)
    const int m    = lane & 15;
    const int g    = lane >> 4;
    const int R0   = blockIdx.x * 32;

    f32x4 acc[6];
    #pragma unroll
    for (int i = 0; i < 6; ++i) acc[i] = (f32x4){0.f, 0.f, 0.f, 0.f};

    float4 xr[2];   // staged x fragments (statically indexed)
    uint4  br[6];   // staged W^T fragments

#define LOADX(kt)                                                                   \
    _Pragma("unroll")                                                               \
    for (int i = 0; i < 2; ++i) {                                                   \
        int id = i * 256 + tid, rX = id >> 4, c4 = id & 15;                         \
        xr[i] = *reinterpret_cast<const float4*>(                                   \
            &x[(size_t)(R0 + rX) * 1024 + (kt) * 64 + c4 * 4]);                     \
    }
#define LOADB(kt)                                                                   \
    _Pragma("unroll")                                                               \
    for (int i = 0; i < 6; ++i) {                                                   \
        int id = i * 256 + tid, nB = id >> 3, cb = id & 7;                          \
        br[i] = *reinterpret_cast<const uint4*>(                                    \
            &wtb[(size_t)nB * 1024 + (kt) * 64 + cb * 8]);                          \
    }
#define WRITE(buf)                                                                  \
    _Pragma("unroll")                                                               \
    for (int i = 0; i < 2; ++i) {                                                   \
        int id = i * 256 + tid, rX = id >> 4, c4 = id & 15;                         \
        int ph = (c4 >> 1) ^ (rX & 7);                                              \
        ushort4 u;                                                                  \
        u.x = f2bf(xr[i].x); u.y = f2bf(xr[i].y);                                   \
        u.z = f2bf(xr[i].z); u.w = f2bf(xr[i].w);                                   \
        *reinterpret_cast<ushort4*>(&xs[buf][rX * 64 + ph * 8 + (c4 & 1) * 4]) = u; \
    }                                                                               \
    _Pragma("unroll")                                                               \
    for (int i = 0; i < 6; ++i) {                                                   \
        int id = i * 256 + tid, nB = id >> 3, cb = id & 7;                          \
        int ph = cb ^ (nB & 7);                                                     \
        *reinterpret_cast<uint4*>(&bs[buf][nB * 64 + ph * 8]) = br[i];              \
    }

    LOADX(0); LOADB(0);
    WRITE(0);
    __syncthreads();

    for (int kt = 0; kt < 16; ++kt) {
        const int cur = kt & 1;
        if (kt < 15) { LOADX(kt + 1); LOADB(kt + 1); }   // fly under compute (T14)
        #pragma unroll
        for (int kk = 0; kk < 2; ++kk) {
            int pc = (4 * kk + g) ^ (m & 7);             // chunk ^ (row&7); row&7==m&7
            bf16x8 a = *reinterpret_cast<const bf16x8*>(&xs[cur][(r * 16 + m) * 64 + pc * 8]);
            #pragma unroll
            for (int nt = 0; nt < 6; ++nt) {
                int n = ch * 96 + nt * 16 + m;
                bf16x8 b = *reinterpret_cast<const bf16x8*>(&bs[cur][n * 64 + pc * 8]);
                acc[nt] = __builtin_amdgcn_mfma_f32_16x16x32_bf16(a, b, acc[nt], 0, 0, 0);
            }
        }
        __syncthreads();
        if (kt < 15) {
            WRITE(cur ^ 1);
            __syncthreads();
        }
    }

    // ---- epilogue: direct bf16 stores (no cross-wave reduction) ----
    #pragma unroll
    for (int nt = 0; nt < 6; ++nt) {
        int c = ch * 96 + nt * 16 + m;                  // global output col [0,192)
        #pragma unroll
        for (int j = 0; j < 4; ++j) {
            size_t row = (size_t)R0 + r * 16 + g * 4 + j;   // C/D: row=(lane>>4)*4+j
            ushort v = f2bf(acc[nt][j]);
            if (c < 128) kq[((size_t)(c >> 6) * BT + row) * 64 + (c & 63)] = v;
            else         vT[(size_t)(c - 128) * BT + row] = v;
        }
    }
#undef LOADX
#undef LOADB
#undef WRITE
}

// ---------------- Kernel 2: flash causal attention, 32-row q-tiles -------------
__global__ __launch_bounds__(256, 3) void attn_kernel3(
    const ushort* __restrict__ qs, const ushort* __restrict__ ks,
    const ushort* __restrict__ vT, float* __restrict__ out)
{
    __shared__ __align__(16) ushort kt[2][64][80];
    __shared__ __align__(16) ushort vt[2][64][80];
    __shared__ __align__(16) ushort pl[4][16][72];

    const int bid = blockIdx.x;
    const int i   = 63 - (bid >> 3);    // q-tile (32 rows), largest first
    const int b   = bid & 7;
    const int Ti  = (i >> 1) + 1;

    const int tid  = threadIdx.x;
    const int lane = tid & 63;
    const int wv   = tid >> 6;
    const int wq   = wv & 1;
    const int hf   = wv >> 1;
    const int m    = lane & 15;
    const int g    = lane >> 4;
    const int ko   = g * 8;
    const int rowb = g * 4;
    const size_t base = (size_t)b * TLEN;
    const int qr0 = i * 32 + wq * 16;

    bf16x8 qa[2];
    {
        size_t row_g = base + qr0 + m;
        qa[0] = *reinterpret_cast<const bf16x8*>(&qs[row_g * 64 + 0 + ko]);
        qa[1] = *reinterpret_cast<const bf16x8*>(&qs[row_g * 64 + 32 + ko]);
    }

    f32x4 o[4];
    #pragma unroll
    for (int nt = 0; nt < 4; ++nt) o[nt] = (f32x4){0.f, 0.f, 0.f, 0.f};
    float mrun[4] = {-1e30f, -1e30f, -1e30f, -1e30f};
    float lrun[4] = {0.f, 0.f, 0.f, 0.f};

    const int hs2 = tid >> 7;
    const int tl  = tid & 127;
    const int sr  = tl >> 1;
    const int sh  = (tl & 1) * 32;

    const int nit = (Ti + 1) >> 1;
    for (int it = 0; it < nit; ++it) {
        int ts = 2 * it + hs2;
        if (ts < Ti) {
            const ushort* ksrc = &ks[(base + (size_t)ts * 64 + sr) * 64 + sh];
            uint4* kdst = reinterpret_cast<uint4*>(&kt[hs2][sr][sh]);
            #pragma unroll
            for (int q = 0; q < 4; ++q) kdst[q] = reinterpret_cast<const uint4*>(ksrc)[q];
            const ushort* vsrc = &vT[(size_t)sr * BT + base + (size_t)ts * 64 + sh];
            uint4* vdst = reinterpret_cast<uint4*>(&vt[hs2][sr][sh]);
            #pragma unroll
            for (int q = 0; q < 4; ++q) vdst[q] = reinterpret_cast<const uint4*>(vsrc)[q];
        }
        __syncthreads();

        int t = 2 * it + hf;
        if (t < Ti) {
            f32x4 s[4];
            #pragma unroll
            for (int nt = 0; nt < 4; ++nt) s[nt] = (f32x4){0.f, 0.f, 0.f, 0.f};
            #pragma unroll
            for (int kk = 0; kk < 2; ++kk) {
                #pragma unroll
                for (int nt = 0; nt < 4; ++nt) {
                    bf16x8 bb = *reinterpret_cast<const bf16x8*>(&kt[hf][nt * 16 + m][kk * 32 + ko]);
                    s[nt] = __builtin_amdgcn_mfma_f32_16x16x32_bf16(qa[kk], bb, s[nt], 0, 0, 0);
                }
            }
            if (t == Ti - 1) {
                #pragma unroll
                for (int nt = 0; nt < 4; ++nt)
                    #pragma unroll
                    for (int j = 0; j < 4; ++j)
                        if (t * 64 + nt * 16 + m > qr0 + rowb + j) s[nt][j] = -1e30f;
            }
            #pragma unroll
            for (int j = 0; j < 4; ++j) {
                float mx = fmaxf(fmaxf(s[0][j], s[1][j]), fmaxf(s[2][j], s[3][j]));
                #pragma unroll
                for (int d = 1; d < 16; d <<= 1) mx = fmaxf(mx, __shfl_xor(mx, d, 64));
                float mnew = fmaxf(mrun[j], mx);
                float corr = __expf(mrun[j] - mnew);
                mrun[j] = mnew;
                float p0 = __expf(s[0][j] - mnew);
                float p1 = __expf(s[1][j] - mnew);
                float p2 = __expf(s[2][j] - mnew);
                float p3 = __expf(s[3][j] - mnew);
                float ps = p0 + p1 + p2 + p3;
                #pragma unroll
                for (int d = 1; d < 16; d <<= 1) ps += __shfl_xor(ps, d, 64);
                lrun[j] = lrun[j] * corr + ps;
                #pragma unroll
                for (int nt = 0; nt < 4; ++nt) o[nt][j] *= corr;
                pl[wv][rowb + j][0 * 16 + m] = f2bf(p0);
                pl[wv][rowb + j][1 * 16 + m] = f2bf(p1);
                pl[wv][rowb + j][2 * 16 + m] = f2bf(p2);
                pl[wv][rowb + j][3 * 16 + m] = f2bf(p3);
            }
            asm volatile("s_waitcnt lgkmcnt(0)" ::: "memory");
            __builtin_amdgcn_sched_barrier(0);
            #pragma unroll
            for (int kk = 0; kk < 2; ++kk) {
                bf16x8 pa = *reinterpret_cast<const bf16x8*>(&pl[wv][m][kk * 32 + ko]);
                #pragma unroll
                for (int nt = 0; nt < 4; ++nt) {
                    bf16x8 vb = *reinterpret_cast<const bf16x8*>(&vt[hf][nt * 16 + m][kk * 32 + ko]);
                    o[nt] = __builtin_amdgcn_mfma_f32_16x16x32_bf16(pa, vb, o[nt], 0, 0, 0);
                }
            }
        }
        __syncthreads();
    }

    float* mg = reinterpret_cast<float*>(&kt[0][0][0]);
    float* st = reinterpret_cast<float*>(&vt[0][0][0]);
    if (hf == 1) {
        #pragma unroll
        for (int nt = 0; nt < 4; ++nt)
            *reinterpret_cast<f32x4*>(&mg[((wq * 4 + nt) * 64 + lane) * 4]) = o[nt];
        if (m == 0) {
            #pragma unroll
            for (int j = 0; j < 4; ++j) {
                st[(wq * 16 + rowb + j) * 2 + 0] = mrun[j];
                st[(wq * 16 + rowb + j) * 2 + 1] = lrun[j];
            }
        }
    }
    __syncthreads();
    if (hf == 0) {
        float ea[4], eb[4], li[4];
        #pragma unroll
        for (int j = 0; j < 4; ++j) {
            float m1 = st[(wq * 16 + rowb + j) * 2 + 0];
            float l1 = st[(wq * 16 + rowb + j) * 2 + 1];
            float mm = fmaxf(mrun[j], m1);
            ea[j] = __expf(mrun[j] - mm);
            eb[j] = __expf(m1 - mm);
            li[j] = 1.0f / (lrun[j] * ea[j] + l1 * eb[j]);
        }
        #pragma unroll
        for (int nt = 0; nt < 4; ++nt) {
            f32x4 ob = *reinterpret_cast<const f32x4*>(&mg[((wq * 4 + nt) * 64 + lane) * 4]);
            #pragma unroll
            for (int j = 0; j < 4; ++j) {
                size_t rrow = base + qr0 + rowb + j;
                out[rrow * 64 + nt * 16 + m] = (o[nt][j] * ea[j] + ob[j] * eb[j]) * li[j];
            }
        }
    }
}

extern "C" void kernel_launch(void* const* d_in, const int* in_sizes, int n_in,
                              void* d_out, int out_size, void* d_ws, size_t ws_size,
                              hipStream_t stream) {
    const float* x  = (const float*)d_in[0];
    const float* Wk = (const float*)d_in[1];
    const float* Wq = (const float*)d_in[2];
    const float* Wv = (const float*)d_in[3];
    float* out = (float*)d_out;

    // ws: K [BT][64] | Q [BT][64] | vT [64][BT]  (bf16, 6 MB) | W^T [192][1024] (384 KB)
    ushort* ws   = (ushort*)d_ws;
    ushort* kq   = ws;
    ushort* kbuf = ws;
    ushort* qbuf = ws + (size_t)BT * 64;
    ushort* vTb  = ws + (size_t)2 * BT * 64;
    ushort* wtb  = ws + (size_t)3 * BT * 64;

    wtrans_kernel<<<dim3(192), 256, 0, stream>>>(Wk, Wq, Wv, wtb);
    qkv_kernel5<<<dim3(512), 256, 0, stream>>>(x, wtb, kq, vTb);
    attn_kernel3<<<dim3(512), 256, 0, stream>>>(qbuf, kbuf, vTb, out);
}